// Round 9
// baseline (233.382 us; speedup 1.0000x reference)
//
#include <hip/hip_runtime.h>

#define N_NODES 100000
#define N_EDGES 1600000
#define F 64

#define NBKT 391                  // coarse buckets = ceil(N/256), bucket = id>>8
#define ABLK 512                  // blocks in fused count+scatter pass (verified best)
#define ECHUNK (N_EDGES / ABLK)   // 3125 edges per block (exact)
#define CAP_B 5120                // fixed bucket capacity (mean 4092, sigma 64 -> +16s)
#define TBLK ((N_NODES + 63) / 64)   // 1563 layer blocks
#define NPAD (TBLK * 64)          // 100032: node rows padded to 64
#define SRC_MASK 0x1FFFF          // low 17 bits hold src (N_NODES < 2^17)
#define ZROW N_NODES              // zeroed fp8 row used as pad-edge target

// csr kernel fused block ranges: csr buckets, then cast, then weight prep
#define CSR_CAST 6250             // N*F/4 / 256 exactly
#define CSR_GRID (NBKT + CSR_CAST + 64)
#define NSLOT 16                  // partial2 accumulation slots

typedef unsigned short u16;
typedef unsigned char u8;
typedef __attribute__((ext_vector_type(8))) short bf16x8;  // 8 bf16 = 4 VGPRs
typedef __attribute__((ext_vector_type(4))) float f32x4;
typedef __attribute__((ext_vector_type(2))) float f32x2;

__device__ __forceinline__ float bf2f(u16 h) {
    return __uint_as_float(((unsigned)h) << 16);
}
__device__ __forceinline__ u16 f2bf(float f) {  // round-to-nearest-even
    unsigned u = __float_as_uint(f);
    u += 0x7FFF + ((u >> 16) & 1);
    return (u16)(u >> 16);
}
__device__ __forceinline__ u8 f2f8(float f) {   // fp8 e4m3 via HW cvt (RNE+sat)
    return (u8)(__builtin_amdgcn_cvt_pk_fp8_f32(f, f, 0, false) & 0xff);
}

// ---- micro-init: cursors + partial2 + fp8 pad rows (1 block, ~3 us) ----
__global__ void init_kernel(int* __restrict__ gcur_d,
                            int* __restrict__ gcur_s,
                            float* __restrict__ partial2,
                            u8* __restrict__ xf8,
                            u8* __restrict__ h1f8) {
    const int t = threadIdx.x;   // 256 threads, 1 block
    for (int i = t; i < NBKT; i += 256) { gcur_d[i] = i * CAP_B; gcur_s[i] = i * CAP_B; }
    for (int i = t; i < (NSLOT * 128 / 4); i += 256)
        ((float4*)partial2)[i] = make_float4(0.f, 0.f, 0.f, 0.f);
    if (t < 128) {  // rows N_NODES..NPAD-1 of both fp8 tables: 2048 B each
        ((uint4*)(xf8 + (size_t)N_NODES * F))[t] = make_uint4(0, 0, 0, 0);
        ((uint4*)(h1f8 + (size_t)N_NODES * F))[t] = make_uint4(0, 0, 0, 0);
    }
}

// One pass with IN-BLOCK COUNTING SORT (round-2 verified config: H-S scan
// with EARLY global reservation overlapping it; burst-contiguous writes).
__global__ void countscat_kernel(const int* __restrict__ edges,
                                 int* __restrict__ gcur_d,
                                 int* __restrict__ gcur_s,
                                 int* __restrict__ ebuf,
                                 u8* __restrict__ sbuf) {
    __shared__ int sS[ECHUNK], sD[ECHUNK], pe[ECHUNK];   // 3 x 12.5 KB
    __shared__ u16 pb[ECHUNK];                           // 6.25 KB
    __shared__ int hd[NBKT], hs[NBKT], cd[NBKT], cs[NBKT], odx[NBKT], cur[NBKT];
    __shared__ int od[512];
    const int tid = threadIdx.x;
    for (int i = tid; i < NBKT; i += 256) { hd[i] = 0; hs[i] = 0; }
    __syncthreads();
    const int base = blockIdx.x * ECHUNK;
    for (int i = tid; i < ECHUNK; i += 256) {  // single global edge read
        int s = edges[base + i];
        int d = edges[N_EDGES + base + i];
        sS[i] = s; sD[i] = d;
        atomicAdd(&hd[d >> 8], 1);
        atomicAdd(&hs[s >> 8], 1);
    }
    __syncthreads();
    for (int i = tid; i < NBKT; i += 256) {  // reserve global ranges EARLY
        cd[i] = atomicAdd(&gcur_d[i], hd[i]);   // latency hides under scans
        cs[i] = atomicAdd(&gcur_s[i], hs[i]);
    }
    // ---- dst pass: scan hd -> place -> burst write ----
    od[tid] = (tid < NBKT) ? hd[tid] : 0;
    od[tid + 256] = (tid + 256 < NBKT) ? hd[tid + 256] : 0;
    __syncthreads();
    for (int o = 1; o < 512; o <<= 1) {
        int t0 = (tid >= o) ? od[tid - o] : 0;
        int t1 = (tid + 256 >= o) ? od[tid + 256 - o] : 0;
        __syncthreads();
        od[tid] += t0; od[tid + 256] += t1;
        __syncthreads();
    }
    for (int i = tid; i < NBKT; i += 256) {
        int ex = od[i] - hd[i];
        odx[i] = ex; cur[i] = ex;
    }
    __syncthreads();
    for (int i = tid; i < ECHUNK; i += 256) {
        int d = sD[i];
        int b = d >> 8;
        int p = atomicAdd(&cur[b], 1);       // LDS atomic only
        pe[p] = ((d & 255) << 17) | sS[i];
        pb[p] = (u16)b;
    }
    __syncthreads();
    for (int k = tid; k < ECHUNK; k += 256) {  // runs contiguous -> coalesced
        int b = pb[k];
        ebuf[cd[b] + (k - odx[b])] = pe[k];
    }
    __syncthreads();
    // ---- src pass (reuse od/odx/cur/pb; payload bytes in pe-as-u8) ----
    od[tid] = (tid < NBKT) ? hs[tid] : 0;
    od[tid + 256] = (tid + 256 < NBKT) ? hs[tid + 256] : 0;
    __syncthreads();
    for (int o = 1; o < 512; o <<= 1) {
        int t0 = (tid >= o) ? od[tid - o] : 0;
        int t1 = (tid + 256 >= o) ? od[tid + 256 - o] : 0;
        __syncthreads();
        od[tid] += t0; od[tid + 256] += t1;
        __syncthreads();
    }
    for (int i = tid; i < NBKT; i += 256) {
        int ex = od[i] - hs[i];
        odx[i] = ex; cur[i] = ex;
    }
    __syncthreads();
    u8* peb = (u8*)pe;
    for (int i = tid; i < ECHUNK; i += 256) {
        int s = sS[i];
        int b = s >> 8;
        int p = atomicAdd(&cur[b], 1);
        peb[p] = (u8)(s & 255);
        pb[p] = (u16)b;
    }
    __syncthreads();
    for (int k = tid; k < ECHUNK; k += 256) {
        int b = pb[k];
        sbuf[cs[b] + (k - odx[b])] = peb[k];
    }
}

// Fused per-bucket finishing + streaming prep tail:
//  blocks [0, NBKT):              dst-CSR build + src outdeg histogram
//  blocks [NBKT, NBKT+CSR_CAST):  x -> xbf(bf16) + xf8(fp8) cast (streams
//                                 behind the latency-bound csr blocks)
//  blocks [NBKT+CSR_CAST, end):   weight prep (wcat1/wcat2)
__global__ void csr_kernel(const int* __restrict__ ebuf,
                           const int* __restrict__ gcur_d,
                           const u8* __restrict__ sbuf,
                           const int* __restrict__ gcur_s,
                           int* __restrict__ row_ptr,
                           int* __restrict__ rdeg,
                           int* __restrict__ col,
                           float* __restrict__ outdegf,
                           const float* __restrict__ x,
                           const float* __restrict__ w_rel1,
                           const float* __restrict__ w_root1,
                           const float* __restrict__ w_rel2,
                           const float* __restrict__ w_root2,
                           u16* __restrict__ xbf, u8* __restrict__ xf8,
                           u16* __restrict__ wcat1, u16* __restrict__ wcat2) {
    __shared__ int eb[CAP_B];
    __shared__ int hist[256];
    __shared__ int shist[256];
    __shared__ int cur[256];
    __shared__ int ws2[4];
    const int b = blockIdx.x;
    const int tid = threadIdx.x;
    if (b >= NBKT) {
        const int bb = b - NBKT;
        if (bb < CSR_CAST) {          // cast path (no LDS use)
            int i = bb * 256 + tid;   // over N*F/4 = 1.6M exactly
            float4 v = ((const float4*)x)[i];
            ushort4 o;
            o.x = f2bf(v.x); o.y = f2bf(v.y); o.z = f2bf(v.z); o.w = f2bf(v.w);
            ((ushort4*)xbf)[i] = o;
            int pk = __builtin_amdgcn_cvt_pk_fp8_f32(v.x, v.y, 0, false);
            pk = __builtin_amdgcn_cvt_pk_fp8_f32(v.z, v.w, pk, true);
            ((int*)xf8)[i] = pk;
        } else {                      // weight prep: wcatL[n][k] n-major bf16
            int idx = (bb - CSR_CAST) * 256 + tid;  // 2*64*128 = 16384
            int which = idx >> 13;
            int r = idx & 8191;
            int n = r >> 7, k = r & 127;
            const float* wr = which ? w_rel2 : w_rel1;
            const float* wo = which ? w_root2 : w_root1;
            float v = (k < 64) ? wr[k * 64 + n] : wo[(k - 64) * 64 + n];
            (which ? wcat2 : wcat1)[r] = f2bf(v);
        }
        return;
    }
    const int lane = tid & 63;
    const int wv = tid >> 6;
    const int base = b * CAP_B;
    hist[tid] = 0; shist[tid] = 0;
    __syncthreads();
    // src outdeg histogram (independent input -> overlaps eb staging stalls)
    const int send = gcur_s[b];
    for (int i = base + tid; i < send; i += 256)
        atomicAdd(&shist[sbuf[i]], 1);
    int count = gcur_d[b] - base;
    if (count > CAP_B) count = CAP_B;  // safety (statistically unreachable)
    for (int i = tid; i < count; i += 256) {
        int ed = ebuf[base + i];
        eb[i] = ed;
        atomicAdd(&hist[(ed >> 17) & 255], 1);
    }
    __syncthreads();
    const int node = b * 256 + tid;
    if (node < N_NODES) outdegf[node] = (float)shist[tid];
    // exclusive scan of hist via wave shfl + 4 wave-sums
    int v = hist[tid];
    int x2 = v;
#pragma unroll
    for (int d = 1; d < 64; d <<= 1) {
        int y = __shfl_up(x2, d, 64);
        if (lane >= d) x2 += y;
    }
    if (lane == 63) ws2[wv] = x2;
    __syncthreads();
    int wb = 0;
    for (int w2 = 0; w2 < wv; w2++) wb += ws2[w2];
    int ex = wb + x2 - v;  // exclusive
    cur[tid] = ex;
    if (node < N_NODES) { row_ptr[node] = base + ex; rdeg[node] = v; }
    __syncthreads();
    for (int i = tid; i < count; i += 256) {
        int ed = eb[i];
        int p = atomicAdd(&cur[(ed >> 17) & 255], 1);  // LDS atomic only
        col[base + p] = ed & SRC_MASK;
    }
}

// ---- FUSED gather + MFMA layer kernels (QUAD-pipelined gather) ----
// Block = 64 nodes, 4 waves; wave wv gathers its 16 nodes in groups of 4:
// four nodes' feature loads in flight together (16 loads/wait, was 8),
// waits per wave 8 -> 4. Pad lanes read zeroed row ZROW (full-width
// batches, no tail in the joint loop). Next quad's col lists prefetched
// during the current quad's accumulation.

#define AT_STR 72   // padded row stride in u16

__device__ __forceinline__ void accum_one(const u8* __restrict__ feat8,
                                          int colv, int e, int g, int i,
                                          float& a0, float& a1,
                                          float& a2, float& a3) {
    int s0 = __shfl(colv, e + g, 64);
    int s1 = __shfl(colv, e + 4 + g, 64);
    int s2 = __shfl(colv, e + 8 + g, 64);
    int s3 = __shfl(colv, e + 12 + g, 64);
    unsigned v0 = *(const unsigned*)(feat8 + (size_t)s0 * F + i * 4);
    unsigned v1 = *(const unsigned*)(feat8 + (size_t)s1 * F + i * 4);
    unsigned v2 = *(const unsigned*)(feat8 + (size_t)s2 * F + i * 4);
    unsigned v3 = *(const unsigned*)(feat8 + (size_t)s3 * F + i * 4);
    f32x2 p0 = __builtin_amdgcn_cvt_pk_f32_fp8((int)v0, false);
    f32x2 p1 = __builtin_amdgcn_cvt_pk_f32_fp8((int)v0, true);
    f32x2 q0 = __builtin_amdgcn_cvt_pk_f32_fp8((int)v1, false);
    f32x2 q1 = __builtin_amdgcn_cvt_pk_f32_fp8((int)v1, true);
    f32x2 r0 = __builtin_amdgcn_cvt_pk_f32_fp8((int)v2, false);
    f32x2 r1 = __builtin_amdgcn_cvt_pk_f32_fp8((int)v2, true);
    f32x2 t0 = __builtin_amdgcn_cvt_pk_f32_fp8((int)v3, false);
    f32x2 t1 = __builtin_amdgcn_cvt_pk_f32_fp8((int)v3, true);
    a0 += (p0.x + q0.x) + (r0.x + t0.x);
    a1 += (p0.y + q0.y) + (r0.y + t0.y);
    a2 += (p1.x + q1.x) + (r1.x + t1.x);
    a3 += (p1.y + q1.y) + (r1.y + t1.y);
}

// accumulate one 16-edge batch for one node (used in the joint quad body)
#define ACC16(CC, A0, A1, A2, A3)                                             \
    do {                                                                      \
        int s0 = __shfl(CC, e + g, 64);                                       \
        int s1 = __shfl(CC, e + 4 + g, 64);                                   \
        int s2 = __shfl(CC, e + 8 + g, 64);                                   \
        int s3 = __shfl(CC, e + 12 + g, 64);                                  \
        unsigned v0 = *(const unsigned*)(feat8 + (size_t)s0 * F + i * 4);     \
        unsigned v1 = *(const unsigned*)(feat8 + (size_t)s1 * F + i * 4);     \
        unsigned v2 = *(const unsigned*)(feat8 + (size_t)s2 * F + i * 4);     \
        unsigned v3 = *(const unsigned*)(feat8 + (size_t)s3 * F + i * 4);     \
        f32x2 p0 = __builtin_amdgcn_cvt_pk_f32_fp8((int)v0, false);           \
        f32x2 p1 = __builtin_amdgcn_cvt_pk_f32_fp8((int)v0, true);            \
        f32x2 q0 = __builtin_amdgcn_cvt_pk_f32_fp8((int)v1, false);           \
        f32x2 q1 = __builtin_amdgcn_cvt_pk_f32_fp8((int)v1, true);            \
        f32x2 r0 = __builtin_amdgcn_cvt_pk_f32_fp8((int)v2, false);           \
        f32x2 r1 = __builtin_amdgcn_cvt_pk_f32_fp8((int)v2, true);            \
        f32x2 t0 = __builtin_amdgcn_cvt_pk_f32_fp8((int)v3, false);           \
        f32x2 t1 = __builtin_amdgcn_cvt_pk_f32_fp8((int)v3, true);            \
        A0 += (p0.x + q0.x) + (r0.x + t0.x);                                  \
        A1 += (p0.y + q0.y) + (r0.y + t0.y);                                  \
        A2 += (p1.x + q1.x) + (r1.x + t1.x);                                  \
        A3 += (p1.y + q1.y) + (r1.y + t1.y);                                  \
    } while (0)

__device__ __forceinline__ void gather_tile(const u8* __restrict__ feat8,
                                            const int* __restrict__ row_ptr,
                                            const int* __restrict__ rdeg,
                                            const int* __restrict__ col,
                                            int node0, int l,
                                            u16 (* __restrict__ tile)[AT_STR]) {
    const int g = l >> 4;
    const int i = l & 15;
    // batch row metadata: 2 coalesced loads for all 16 nodes
    int rp = 0, rd = 0;
    {
        int n = node0 + l;
        bool v = (l < 16) && (n < N_NODES);
        rp = v ? row_ptr[n] : 0;
        rd = v ? rdeg[n] : 0;
    }
    // prefetch quad 0 col lists (pad lanes -> ZROW = zeroed feature row)
    int begA = __shfl(rp, 0, 64), degA = __shfl(rd, 0, 64);
    int begB = __shfl(rp, 1, 64), degB = __shfl(rd, 1, 64);
    int begC = __shfl(rp, 2, 64), degC = __shfl(rd, 2, 64);
    int begD = __shfl(rp, 3, 64), degD = __shfl(rd, 3, 64);
    int colvA = (l < min(degA, 64)) ? col[begA + l] : (int)ZROW;
    int colvB = (l < min(degB, 64)) ? col[begB + l] : (int)ZROW;
    int colvC = (l < min(degC, 64)) ? col[begC + l] : (int)ZROW;
    int colvD = (l < min(degD, 64)) ? col[begD + l] : (int)ZROW;
    for (int r = 0; r < 16; r += 4) {
        const int cbegA = begA, cdegA = degA, ccolA = colvA;
        const int cbegB = begB, cdegB = degB, ccolB = colvB;
        const int cbegC = begC, cdegC = degC, ccolC = colvC;
        const int cbegD = begD, cdegD = degD, ccolD = colvD;
        if (r < 12) {   // prefetch next quad (col latency hides under feats)
            begA = __shfl(rp, r + 4, 64); degA = __shfl(rd, r + 4, 64);
            begB = __shfl(rp, r + 5, 64); degB = __shfl(rd, r + 5, 64);
            begC = __shfl(rp, r + 6, 64); degC = __shfl(rd, r + 6, 64);
            begD = __shfl(rp, r + 7, 64); degD = __shfl(rd, r + 7, 64);
            colvA = (l < min(degA, 64)) ? col[begA + l] : (int)ZROW;
            colvB = (l < min(degB, 64)) ? col[begB + l] : (int)ZROW;
            colvC = (l < min(degC, 64)) ? col[begC + l] : (int)ZROW;
            colvD = (l < min(degD, 64)) ? col[begD + l] : (int)ZROW;
        }
        const int nbA = (min(cdegA, 64) + 15) & ~15;   // full 16-batches (ZROW pad)
        const int nbB = (min(cdegB, 64) + 15) & ~15;
        const int nbC = (min(cdegC, 64) + 15) & ~15;
        const int nbD = (min(cdegD, 64) + 15) & ~15;
        const int nbmin = min(min(nbA, nbB), min(nbC, nbD));
        float aA0 = 0.f, aA1 = 0.f, aA2 = 0.f, aA3 = 0.f;
        float aB0 = 0.f, aB1 = 0.f, aB2 = 0.f, aB3 = 0.f;
        float aC0 = 0.f, aC1 = 0.f, aC2 = 0.f, aC3 = 0.f;
        float aD0 = 0.f, aD1 = 0.f, aD2 = 0.f, aD3 = 0.f;
        int e = 0;
        for (; e < nbmin; e += 16) {   // joint: 16 independent loads in flight
            ACC16(ccolA, aA0, aA1, aA2, aA3);
            ACC16(ccolB, aB0, aB1, aB2, aB3);
            ACC16(ccolC, aC0, aC1, aC2, aC3);
            ACC16(ccolD, aD0, aD1, aD2, aD3);
        }
        for (int eA = e; eA < nbA; eA += 16)
            accum_one(feat8, ccolA, eA, g, i, aA0, aA1, aA2, aA3);
        for (int eB = e; eB < nbB; eB += 16)
            accum_one(feat8, ccolB, eB, g, i, aB0, aB1, aB2, aB3);
        for (int eC = e; eC < nbC; eC += 16)
            accum_one(feat8, ccolC, eC, g, i, aC0, aC1, aC2, aC3);
        for (int eD = e; eD < nbD; eD += 16)
            accum_one(feat8, ccolD, eD, g, i, aD0, aD1, aD2, aD3);
        // deep rows (deg > 64): statistically never, kept for correctness
        for (int b2 = 64; b2 < cdegA; b2 += 64) {
            int c2 = min(cdegA - b2, 64);
            int cv = (l < c2) ? col[cbegA + b2 + l] : (int)ZROW;
            int nb2 = (c2 + 15) & ~15;
            for (int e2 = 0; e2 < nb2; e2 += 16)
                accum_one(feat8, cv, e2, g, i, aA0, aA1, aA2, aA3);
        }
        for (int b2 = 64; b2 < cdegB; b2 += 64) {
            int c2 = min(cdegB - b2, 64);
            int cv = (l < c2) ? col[cbegB + b2 + l] : (int)ZROW;
            int nb2 = (c2 + 15) & ~15;
            for (int e2 = 0; e2 < nb2; e2 += 16)
                accum_one(feat8, cv, e2, g, i, aB0, aB1, aB2, aB3);
        }
        for (int b2 = 64; b2 < cdegC; b2 += 64) {
            int c2 = min(cdegC - b2, 64);
            int cv = (l < c2) ? col[cbegC + b2 + l] : (int)ZROW;
            int nb2 = (c2 + 15) & ~15;
            for (int e2 = 0; e2 < nb2; e2 += 16)
                accum_one(feat8, cv, e2, g, i, aC0, aC1, aC2, aC3);
        }
        for (int b2 = 64; b2 < cdegD; b2 += 64) {
            int c2 = min(cdegD - b2, 64);
            int cv = (l < c2) ? col[cbegD + b2 + l] : (int)ZROW;
            int nb2 = (c2 + 15) & ~15;
            for (int e2 = 0; e2 < nb2; e2 += 16)
                accum_one(feat8, cv, e2, g, i, aD0, aD1, aD2, aD3);
        }
        // reduce quads and store all four nodes
        aA0 += __shfl_xor(aA0, 16, 64); aA0 += __shfl_xor(aA0, 32, 64);
        aA1 += __shfl_xor(aA1, 16, 64); aA1 += __shfl_xor(aA1, 32, 64);
        aA2 += __shfl_xor(aA2, 16, 64); aA2 += __shfl_xor(aA2, 32, 64);
        aA3 += __shfl_xor(aA3, 16, 64); aA3 += __shfl_xor(aA3, 32, 64);
        aB0 += __shfl_xor(aB0, 16, 64); aB0 += __shfl_xor(aB0, 32, 64);
        aB1 += __shfl_xor(aB1, 16, 64); aB1 += __shfl_xor(aB1, 32, 64);
        aB2 += __shfl_xor(aB2, 16, 64); aB2 += __shfl_xor(aB2, 32, 64);
        aB3 += __shfl_xor(aB3, 16, 64); aB3 += __shfl_xor(aB3, 32, 64);
        aC0 += __shfl_xor(aC0, 16, 64); aC0 += __shfl_xor(aC0, 32, 64);
        aC1 += __shfl_xor(aC1, 16, 64); aC1 += __shfl_xor(aC1, 32, 64);
        aC2 += __shfl_xor(aC2, 16, 64); aC2 += __shfl_xor(aC2, 32, 64);
        aC3 += __shfl_xor(aC3, 16, 64); aC3 += __shfl_xor(aC3, 32, 64);
        aD0 += __shfl_xor(aD0, 16, 64); aD0 += __shfl_xor(aD0, 32, 64);
        aD1 += __shfl_xor(aD1, 16, 64); aD1 += __shfl_xor(aD1, 32, 64);
        aD2 += __shfl_xor(aD2, 16, 64); aD2 += __shfl_xor(aD2, 32, 64);
        aD3 += __shfl_xor(aD3, 16, 64); aD3 += __shfl_xor(aD3, 32, 64);
        if (g == 0) {
            ushort4 oA, oB, oC, oD;
            oA.x = f2bf(aA0); oA.y = f2bf(aA1); oA.z = f2bf(aA2); oA.w = f2bf(aA3);
            oB.x = f2bf(aB0); oB.y = f2bf(aB1); oB.z = f2bf(aB2); oB.w = f2bf(aB3);
            oC.x = f2bf(aC0); oC.y = f2bf(aC1); oC.z = f2bf(aC2); oC.w = f2bf(aC3);
            oD.x = f2bf(aD0); oD.y = f2bf(aD1); oD.z = f2bf(aD2); oD.w = f2bf(aD3);
            *(ushort4*)&tile[r][i * 4] = oA;       // zeros for pad/deg-0 nodes
            *(ushort4*)&tile[r + 1][i * 4] = oB;
            *(ushort4*)&tile[r + 2][i * 4] = oC;
            *(ushort4*)&tile[r + 3][i * 4] = oD;
        }
    }
}

__global__ void layer1_kernel(const u8* __restrict__ feat8,   // xf8
                              const u16* __restrict__ xbf,    // root input
                              const int* __restrict__ row_ptr,
                              const int* __restrict__ rdeg,
                              const int* __restrict__ col,
                              const u16* __restrict__ wcat,
                              const float* __restrict__ b_rel,
                              u16* __restrict__ h1bf,
                              u8* __restrict__ h1f8) {
    __shared__ u16 atile[4][16][AT_STR];   // 9.2 KB
    const int l = threadIdx.x & 63;
    const int wv = threadIdx.x >> 6;
    const int node0 = blockIdx.x * 64 + wv * 16;
    const int c = l & 15, quad = l >> 4;

    // hoist gather-independent loads: root fragments + bias hide under gather
    const size_t xrow = (size_t)(node0 + c) * F + quad * 8;  // pad rows masked below
    bf16x8 fa2 = *(const bf16x8*)(xbf + xrow);
    bf16x8 fa3 = *(const bf16x8*)(xbf + xrow + 32);
    float bias[4];
#pragma unroll
    for (int nt = 0; nt < 4; nt++) bias[nt] = b_rel[nt * 16 + c];

    gather_tile(feat8, row_ptr, rdeg, col, node0, l, atile[wv]);
    __syncthreads();

    // ---- MFMA: A = [aggr(LDS) | x(global)] ----
    bf16x8 fa0 = *(const bf16x8*)(&atile[wv][c][quad * 8]);
    bf16x8 fa1 = *(const bf16x8*)(&atile[wv][c][quad * 8 + 32]);

    f32x4 acc[4];
#pragma unroll
    for (int nt = 0; nt < 4; nt++) {
        const u16* wp = wcat + (size_t)(nt * 16 + c) * 128 + quad * 8;
        bf16x8 b0 = *(const bf16x8*)(wp);
        bf16x8 b1 = *(const bf16x8*)(wp + 32);
        bf16x8 b2 = *(const bf16x8*)(wp + 64);
        bf16x8 b3 = *(const bf16x8*)(wp + 96);
        f32x4 d = {0.f, 0.f, 0.f, 0.f};
        d = __builtin_amdgcn_mfma_f32_16x16x32_bf16(fa0, b0, d, 0, 0, 0);
        d = __builtin_amdgcn_mfma_f32_16x16x32_bf16(fa1, b1, d, 0, 0, 0);
        d = __builtin_amdgcn_mfma_f32_16x16x32_bf16(fa2, b2, d, 0, 0, 0);
        d = __builtin_amdgcn_mfma_f32_16x16x32_bf16(fa3, b3, d, 0, 0, 0);
        acc[nt] = d;
    }
#pragma unroll
    for (int nt = 0; nt < 4; nt++) {
        int f = nt * 16 + c;
#pragma unroll
        for (int r = 0; r < 4; r++) {
            int node = node0 + quad * 4 + r;
            if (node < N_NODES) {
                float v = fmaxf(acc[nt][r] + bias[nt], 0.f);
                h1bf[(size_t)node * F + f] = f2bf(v);
                h1f8[(size_t)node * F + f] = f2f8(v);
            }
        }
    }
}

__global__ void layer2_kernel(const u8* __restrict__ feat8,   // h1f8
                              const u16* __restrict__ h1bf,   // root input
                              const int* __restrict__ row_ptr,
                              const int* __restrict__ rdeg,
                              const int* __restrict__ col,
                              const u16* __restrict__ wcat,
                              const float* __restrict__ b_rel,
                              const float* __restrict__ outdegf,
                              float* __restrict__ partial2) {
    __shared__ u16 atile[4][16][AT_STR];   // 9.2 KB
    __shared__ float sR1[256], sR2[256];
    const int l = threadIdx.x & 63;
    const int wv = threadIdx.x >> 6;
    const int node0 = blockIdx.x * 64 + wv * 16;
    const int c = l & 15, quad = l >> 4;

    // hoist gather-independent loads
    const size_t xrow = (size_t)(node0 + c) * F + quad * 8;
    bf16x8 fa2 = *(const bf16x8*)(h1bf + xrow);
    bf16x8 fa3 = *(const bf16x8*)(h1bf + xrow + 32);
    float bias[4];
#pragma unroll
    for (int nt = 0; nt < 4; nt++) bias[nt] = b_rel[nt * 16 + c];
    float deg[4], val[4];
#pragma unroll
    for (int r = 0; r < 4; r++) {
        int node = node0 + quad * 4 + r;
        bool v = node < N_NODES;
        deg[r] = v ? outdegf[node] : 0.f;
        val[r] = v ? 1.f : 0.f;
    }

    gather_tile(feat8, row_ptr, rdeg, col, node0, l, atile[wv]);
    __syncthreads();

    bf16x8 fa0 = *(const bf16x8*)(&atile[wv][c][quad * 8]);
    bf16x8 fa1 = *(const bf16x8*)(&atile[wv][c][quad * 8 + 32]);

    f32x4 acc[4];
#pragma unroll
    for (int nt = 0; nt < 4; nt++) {
        const u16* wp = wcat + (size_t)(nt * 16 + c) * 128 + quad * 8;
        bf16x8 b0 = *(const bf16x8*)(wp);
        bf16x8 b1 = *(const bf16x8*)(wp + 32);
        bf16x8 b2 = *(const bf16x8*)(wp + 64);
        bf16x8 b3 = *(const bf16x8*)(wp + 96);
        f32x4 d = {0.f, 0.f, 0.f, 0.f};
        d = __builtin_amdgcn_mfma_f32_16x16x32_bf16(fa0, b0, d, 0, 0, 0);
        d = __builtin_amdgcn_mfma_f32_16x16x32_bf16(fa1, b1, d, 0, 0, 0);
        d = __builtin_amdgcn_mfma_f32_16x16x32_bf16(fa2, b2, d, 0, 0, 0);
        d = __builtin_amdgcn_mfma_f32_16x16x32_bf16(fa3, b3, d, 0, 0, 0);
        acc[nt] = d;
    }

    // collapsed layer-3: {sum outdeg*h2, sum h2} -> 16 global atomic slots
    float s1[4], s2[4];
#pragma unroll
    for (int nt = 0; nt < 4; nt++) {
        float t1 = 0.f, t2 = 0.f;
#pragma unroll
        for (int r = 0; r < 4; r++) {
            float v = fmaxf(acc[nt][r] + bias[nt], 0.f);  // relu kills pad noise
            t1 += deg[r] * v;
            t2 += val[r] * v;
        }
        t1 += __shfl_xor(t1, 16, 64);
        t1 += __shfl_xor(t1, 32, 64);
        t2 += __shfl_xor(t2, 16, 64);
        t2 += __shfl_xor(t2, 32, 64);
        s1[nt] = t1;
        s2[nt] = t2;
    }
    if (quad == 0) {
#pragma unroll
        for (int nt = 0; nt < 4; nt++) {
            sR1[wv * 64 + nt * 16 + c] = s1[nt];
            sR2[wv * 64 + nt * 16 + c] = s2[nt];
        }
    }
    __syncthreads();
    if (threadIdx.x < 64) {
        int f = threadIdx.x;
        float p1 = sR1[f] + sR1[64 + f] + sR1[128 + f] + sR1[192 + f];
        float p2 = sR2[f] + sR2[64 + f] + sR2[128 + f] + sR2[192 + f];
        const int slot = (blockIdx.x & (NSLOT - 1)) * 128;  // ~98 blocks/addr
        atomicAdd(&partial2[slot + f], p1);
        atomicAdd(&partial2[slot + 64 + f], p2);
    }
}

// Final: out = (S1 . w_rel3 + S2 . w_root3)/N + b3 from NSLOT x 128 partials.
__global__ void final_kernel(const float* __restrict__ partial2,
                             const float* __restrict__ w_rel3,
                             const float* __restrict__ b_rel3,
                             const float* __restrict__ w_root3,
                             float* __restrict__ out) {
    __shared__ float sT[128];
    const int t = threadIdx.x;  // 128 threads
    float s = 0.f;
#pragma unroll
    for (int k = 0; k < NSLOT; k++) s += partial2[k * 128 + t];
    sT[t] = s;
    __syncthreads();
    if (t < 64) {
        float v = sT[t] * w_rel3[t] + sT[64 + t] * w_root3[t];
        for (int off = 32; off > 0; off >>= 1) v += __shfl_down(v, off);
        if (t == 0) out[0] = v * (1.0f / (float)N_NODES) + b_rel3[0];
    }
}

extern "C" void kernel_launch(void* const* d_in, const int* in_sizes, int n_in,
                              void* d_out, int out_size, void* d_ws, size_t ws_size,
                              hipStream_t stream) {
    const float* x       = (const float*)d_in[0];
    const int*   edges   = (const int*)d_in[1];   // [2, E]: src row then dst row
    const float* w_rel1  = (const float*)d_in[2];
    const float* b_rel1  = (const float*)d_in[3];
    const float* w_root1 = (const float*)d_in[4];
    const float* w_rel2  = (const float*)d_in[5];
    const float* b_rel2  = (const float*)d_in[6];
    const float* w_root2 = (const float*)d_in[7];
    const float* w_rel3  = (const float*)d_in[8];
    const float* b_rel3  = (const float*)d_in[9];
    const float* w_root3 = (const float*)d_in[10];
    float* out = (float*)d_out;

    const size_t nfp = (size_t)NPAD * F;  // padded rows for maskless MFMA A-loads
    char* p = (char*)d_ws;
    u16*   xbf      = (u16*)p;                p += nfp * 2;                 // 12.8 MB
    u16*   h1bf     = (u16*)p;                p += nfp * 2;                 // 12.8 MB
    u8*    xf8      = (u8*)p;                 p += nfp;                     // 6.4 MB
    u8*    h1f8     = (u8*)p;                 p += nfp;                     // 6.4 MB
    int*   row_ptr  = (int*)p;                p += (size_t)N_NODES * 4;     // 0.4 MB
    int*   rdeg     = (int*)p;                p += (size_t)N_NODES * 4;     // 0.4 MB
    int*   col      = (int*)p;                p += (size_t)NBKT * CAP_B * 4; // 8.0 MB
    int*   ebuf     = (int*)p;                p += (size_t)NBKT * CAP_B * 4; // 8.0 MB
    int*   gcur_d   = (int*)p;                p += NBKT * 4;
    int*   gcur_s   = (int*)p;                p += NBKT * 4 + 8;            // pad align
    float* outdegf  = (float*)p;              p += (size_t)N_NODES * 4;     // 0.4 MB
    float* partial2 = (float*)p;              p += (size_t)NSLOT * 128 * 4; // 8 KB
    u16*   wcat1    = (u16*)p;                p += 64 * 128 * 2;            // 16 KB
    u16*   wcat2    = (u16*)p;                p += 64 * 128 * 2;            // 16 KB
    u8*    sbuf     = (u8*)p;                                              // 2.0 MB

    // ---- micro-init: cursors + partial2 + fp8 pad rows ----
    init_kernel<<<1, 256, 0, stream>>>(gcur_d, gcur_s, partial2, xf8, h1f8);

    // ---- counting sort: dst-CSR + src outdeg (burst writes, no glb atomics) ----
    countscat_kernel<<<ABLK, 256, 0, stream>>>(edges, gcur_d, gcur_s, ebuf, sbuf);

    // ---- csr finishing + cast/wprep streamed behind it ----
    csr_kernel<<<CSR_GRID, 256, 0, stream>>>(ebuf, gcur_d, sbuf, gcur_s,
                                             row_ptr, rdeg, col, outdegf,
                                             x, w_rel1, w_root1, w_rel2, w_root2,
                                             xbf, xf8, wcat1, wcat2);

    // layer 1: fused gather + transform (aggr never materialized)
    layer1_kernel<<<TBLK, 256, 0, stream>>>(xf8, xbf, row_ptr, rdeg, col,
                                            wcat1, b_rel1, h1bf, h1f8);

    // layer 2 + collapsed layer 3 (h2 never materialized)
    layer2_kernel<<<TBLK, 256, 0, stream>>>(h1f8, h1bf, row_ptr, rdeg, col,
                                            wcat2, b_rel2, outdegf, partial2);

    // single tiny final reduction
    final_kernel<<<1, 128, 0, stream>>>(partial2, w_rel3, b_rel3, w_root3, out);
}

// Round 10
// 226.806 us; speedup vs baseline: 1.0290x; 1.0290x over previous
//
#include <hip/hip_runtime.h>

#define N_NODES 100000
#define N_EDGES 1600000
#define F 64

#define NBKT 391                  // coarse buckets = ceil(N/256), bucket = id>>8
#define ABLK 512                  // blocks in fused count+scatter pass (verified best)
#define ECHUNK (N_EDGES / ABLK)   // 3125 edges per block (exact)
#define CAP_B 5120                // fixed bucket capacity (mean 4092, sigma 64 -> +16s)
#define TBLK ((N_NODES + 63) / 64)   // 1563 layer blocks
#define NPAD (TBLK * 64)          // 100032: node rows padded to 64
#define SRC_MASK 0x1FFFF          // low 17 bits hold src (N_NODES < 2^17)
#define ZROW N_NODES              // zeroed fp8 row used as pad-edge target

// csr kernel fused block ranges: csr buckets, then cast, then weight prep
#define CSR_CAST 6250             // N*F/4 / 256 exactly
#define CSR_GRID (NBKT + CSR_CAST + 64)
#define NSLOT 16                  // partial2 accumulation slots

typedef unsigned short u16;
typedef unsigned char u8;
typedef __attribute__((ext_vector_type(8))) short bf16x8;  // 8 bf16 = 4 VGPRs
typedef __attribute__((ext_vector_type(4))) float f32x4;
typedef __attribute__((ext_vector_type(2))) float f32x2;

__device__ __forceinline__ float bf2f(u16 h) {
    return __uint_as_float(((unsigned)h) << 16);
}
__device__ __forceinline__ u16 f2bf(float f) {  // round-to-nearest-even
    unsigned u = __float_as_uint(f);
    u += 0x7FFF + ((u >> 16) & 1);
    return (u16)(u >> 16);
}
__device__ __forceinline__ u8 f2f8(float f) {   // fp8 e4m3 via HW cvt (RNE+sat)
    return (u8)(__builtin_amdgcn_cvt_pk_fp8_f32(f, f, 0, false) & 0xff);
}

// ---- micro-init: cursors + partial2 + fp8 pad rows (1 block, ~3 us) ----
__global__ void init_kernel(int* __restrict__ gcur_d,
                            int* __restrict__ gcur_s,
                            float* __restrict__ partial2,
                            u8* __restrict__ xf8,
                            u8* __restrict__ h1f8) {
    const int t = threadIdx.x;   // 256 threads, 1 block
    for (int i = t; i < NBKT; i += 256) { gcur_d[i] = i * CAP_B; gcur_s[i] = i * CAP_B; }
    for (int i = t; i < (NSLOT * 128 / 4); i += 256)
        ((float4*)partial2)[i] = make_float4(0.f, 0.f, 0.f, 0.f);
    if (t < 128) {  // rows N_NODES..NPAD-1 of both fp8 tables: 2048 B each
        ((uint4*)(xf8 + (size_t)N_NODES * F))[t] = make_uint4(0, 0, 0, 0);
        ((uint4*)(h1f8 + (size_t)N_NODES * F))[t] = make_uint4(0, 0, 0, 0);
    }
}

// One pass with IN-BLOCK COUNTING SORT (round-2 verified config: H-S scan
// with EARLY global reservation overlapping it; burst-contiguous writes).
__global__ void countscat_kernel(const int* __restrict__ edges,
                                 int* __restrict__ gcur_d,
                                 int* __restrict__ gcur_s,
                                 int* __restrict__ ebuf,
                                 u8* __restrict__ sbuf) {
    __shared__ int sS[ECHUNK], sD[ECHUNK], pe[ECHUNK];   // 3 x 12.5 KB
    __shared__ u16 pb[ECHUNK];                           // 6.25 KB
    __shared__ int hd[NBKT], hs[NBKT], cd[NBKT], cs[NBKT], odx[NBKT], cur[NBKT];
    __shared__ int od[512];
    const int tid = threadIdx.x;
    for (int i = tid; i < NBKT; i += 256) { hd[i] = 0; hs[i] = 0; }
    __syncthreads();
    const int base = blockIdx.x * ECHUNK;
    for (int i = tid; i < ECHUNK; i += 256) {  // single global edge read
        int s = edges[base + i];
        int d = edges[N_EDGES + base + i];
        sS[i] = s; sD[i] = d;
        atomicAdd(&hd[d >> 8], 1);
        atomicAdd(&hs[s >> 8], 1);
    }
    __syncthreads();
    for (int i = tid; i < NBKT; i += 256) {  // reserve global ranges EARLY
        cd[i] = atomicAdd(&gcur_d[i], hd[i]);   // latency hides under scans
        cs[i] = atomicAdd(&gcur_s[i], hs[i]);
    }
    // ---- dst pass: scan hd -> place -> burst write ----
    od[tid] = (tid < NBKT) ? hd[tid] : 0;
    od[tid + 256] = (tid + 256 < NBKT) ? hd[tid + 256] : 0;
    __syncthreads();
    for (int o = 1; o < 512; o <<= 1) {
        int t0 = (tid >= o) ? od[tid - o] : 0;
        int t1 = (tid + 256 >= o) ? od[tid + 256 - o] : 0;
        __syncthreads();
        od[tid] += t0; od[tid + 256] += t1;
        __syncthreads();
    }
    for (int i = tid; i < NBKT; i += 256) {
        int ex = od[i] - hd[i];
        odx[i] = ex; cur[i] = ex;
    }
    __syncthreads();
    for (int i = tid; i < ECHUNK; i += 256) {
        int d = sD[i];
        int b = d >> 8;
        int p = atomicAdd(&cur[b], 1);       // LDS atomic only
        pe[p] = ((d & 255) << 17) | sS[i];
        pb[p] = (u16)b;
    }
    __syncthreads();
    for (int k = tid; k < ECHUNK; k += 256) {  // runs contiguous -> coalesced
        int b = pb[k];
        ebuf[cd[b] + (k - odx[b])] = pe[k];
    }
    __syncthreads();
    // ---- src pass (reuse od/odx/cur/pb; payload bytes in pe-as-u8) ----
    od[tid] = (tid < NBKT) ? hs[tid] : 0;
    od[tid + 256] = (tid + 256 < NBKT) ? hs[tid + 256] : 0;
    __syncthreads();
    for (int o = 1; o < 512; o <<= 1) {
        int t0 = (tid >= o) ? od[tid - o] : 0;
        int t1 = (tid + 256 >= o) ? od[tid + 256 - o] : 0;
        __syncthreads();
        od[tid] += t0; od[tid + 256] += t1;
        __syncthreads();
    }
    for (int i = tid; i < NBKT; i += 256) {
        int ex = od[i] - hs[i];
        odx[i] = ex; cur[i] = ex;
    }
    __syncthreads();
    u8* peb = (u8*)pe;
    for (int i = tid; i < ECHUNK; i += 256) {
        int s = sS[i];
        int b = s >> 8;
        int p = atomicAdd(&cur[b], 1);
        peb[p] = (u8)(s & 255);
        pb[p] = (u16)b;
    }
    __syncthreads();
    for (int k = tid; k < ECHUNK; k += 256) {
        int b = pb[k];
        sbuf[cs[b] + (k - odx[b])] = peb[k];
    }
}

// Fused per-bucket finishing + streaming prep tail:
//  blocks [0, NBKT):              dst-CSR build + src outdeg histogram
//  blocks [NBKT, NBKT+CSR_CAST):  x -> xbf(bf16) + xf8(fp8) cast (streams
//                                 behind the latency-bound csr blocks)
//  blocks [NBKT+CSR_CAST, end):   weight prep (wcat1/wcat2)
__global__ void csr_kernel(const int* __restrict__ ebuf,
                           const int* __restrict__ gcur_d,
                           const u8* __restrict__ sbuf,
                           const int* __restrict__ gcur_s,
                           int* __restrict__ row_ptr,
                           int* __restrict__ rdeg,
                           int* __restrict__ col,
                           float* __restrict__ outdegf,
                           const float* __restrict__ x,
                           const float* __restrict__ w_rel1,
                           const float* __restrict__ w_root1,
                           const float* __restrict__ w_rel2,
                           const float* __restrict__ w_root2,
                           u16* __restrict__ xbf, u8* __restrict__ xf8,
                           u16* __restrict__ wcat1, u16* __restrict__ wcat2) {
    __shared__ int eb[CAP_B];
    __shared__ int hist[256];
    __shared__ int shist[256];
    __shared__ int cur[256];
    __shared__ int ws2[4];
    const int b = blockIdx.x;
    const int tid = threadIdx.x;
    if (b >= NBKT) {
        const int bb = b - NBKT;
        if (bb < CSR_CAST) {          // cast path (no LDS use)
            int i = bb * 256 + tid;   // over N*F/4 = 1.6M exactly
            float4 v = ((const float4*)x)[i];
            ushort4 o;
            o.x = f2bf(v.x); o.y = f2bf(v.y); o.z = f2bf(v.z); o.w = f2bf(v.w);
            ((ushort4*)xbf)[i] = o;
            int pk = __builtin_amdgcn_cvt_pk_fp8_f32(v.x, v.y, 0, false);
            pk = __builtin_amdgcn_cvt_pk_fp8_f32(v.z, v.w, pk, true);
            ((int*)xf8)[i] = pk;
        } else {                      // weight prep: wcatL[n][k] n-major bf16
            int idx = (bb - CSR_CAST) * 256 + tid;  // 2*64*128 = 16384
            int which = idx >> 13;
            int r = idx & 8191;
            int n = r >> 7, k = r & 127;
            const float* wr = which ? w_rel2 : w_rel1;
            const float* wo = which ? w_root2 : w_root1;
            float v = (k < 64) ? wr[k * 64 + n] : wo[(k - 64) * 64 + n];
            (which ? wcat2 : wcat1)[r] = f2bf(v);
        }
        return;
    }
    const int lane = tid & 63;
    const int wv = tid >> 6;
    const int base = b * CAP_B;
    hist[tid] = 0; shist[tid] = 0;
    __syncthreads();
    // src outdeg histogram (independent input -> overlaps eb staging stalls)
    const int send = gcur_s[b];
    for (int i = base + tid; i < send; i += 256)
        atomicAdd(&shist[sbuf[i]], 1);
    int count = gcur_d[b] - base;
    if (count > CAP_B) count = CAP_B;  // safety (statistically unreachable)
    for (int i = tid; i < count; i += 256) {
        int ed = ebuf[base + i];
        eb[i] = ed;
        atomicAdd(&hist[(ed >> 17) & 255], 1);
    }
    __syncthreads();
    const int node = b * 256 + tid;
    if (node < N_NODES) outdegf[node] = (float)shist[tid];
    // exclusive scan of hist via wave shfl + 4 wave-sums
    int v = hist[tid];
    int x2 = v;
#pragma unroll
    for (int d = 1; d < 64; d <<= 1) {
        int y = __shfl_up(x2, d, 64);
        if (lane >= d) x2 += y;
    }
    if (lane == 63) ws2[wv] = x2;
    __syncthreads();
    int wb = 0;
    for (int w2 = 0; w2 < wv; w2++) wb += ws2[w2];
    int ex = wb + x2 - v;  // exclusive
    cur[tid] = ex;
    if (node < N_NODES) { row_ptr[node] = base + ex; rdeg[node] = v; }
    __syncthreads();
    for (int i = tid; i < count; i += 256) {
        int ed = eb[i];
        int p = atomicAdd(&cur[(ed >> 17) & 255], 1);  // LDS atomic only
        col[base + p] = ed & SRC_MASK;
    }
}

// ---- FUSED gather + MFMA layer kernels (PAIR-pipelined gather, nbmax) ----
// Block = 64 nodes, 4 waves; wave wv gathers its 16 nodes in PAIRS with both
// nodes running the JOINT loop to nbmax (8 loads in flight per wait, waits
// per wave = sum(nbmax)/16 ~ 8, no ragged serial leftovers). The exhausted
// node's pad batches read the zeroed row ZROW -> L1-hit broadcast, ~free.
// Next pair's col lists prefetched during the current pair's accumulation.

#define AT_STR 72   // padded row stride in u16

__device__ __forceinline__ void accum_one(const u8* __restrict__ feat8,
                                          int colv, int e, int g, int i,
                                          float& a0, float& a1,
                                          float& a2, float& a3) {
    int s0 = __shfl(colv, e + g, 64);
    int s1 = __shfl(colv, e + 4 + g, 64);
    int s2 = __shfl(colv, e + 8 + g, 64);
    int s3 = __shfl(colv, e + 12 + g, 64);
    unsigned v0 = *(const unsigned*)(feat8 + (size_t)s0 * F + i * 4);
    unsigned v1 = *(const unsigned*)(feat8 + (size_t)s1 * F + i * 4);
    unsigned v2 = *(const unsigned*)(feat8 + (size_t)s2 * F + i * 4);
    unsigned v3 = *(const unsigned*)(feat8 + (size_t)s3 * F + i * 4);
    f32x2 p0 = __builtin_amdgcn_cvt_pk_f32_fp8((int)v0, false);
    f32x2 p1 = __builtin_amdgcn_cvt_pk_f32_fp8((int)v0, true);
    f32x2 q0 = __builtin_amdgcn_cvt_pk_f32_fp8((int)v1, false);
    f32x2 q1 = __builtin_amdgcn_cvt_pk_f32_fp8((int)v1, true);
    f32x2 r0 = __builtin_amdgcn_cvt_pk_f32_fp8((int)v2, false);
    f32x2 r1 = __builtin_amdgcn_cvt_pk_f32_fp8((int)v2, true);
    f32x2 t0 = __builtin_amdgcn_cvt_pk_f32_fp8((int)v3, false);
    f32x2 t1 = __builtin_amdgcn_cvt_pk_f32_fp8((int)v3, true);
    a0 += (p0.x + q0.x) + (r0.x + t0.x);
    a1 += (p0.y + q0.y) + (r0.y + t0.y);
    a2 += (p1.x + q1.x) + (r1.x + t1.x);
    a3 += (p1.y + q1.y) + (r1.y + t1.y);
}

__device__ __forceinline__ void gather_tile(const u8* __restrict__ feat8,
                                            const int* __restrict__ row_ptr,
                                            const int* __restrict__ rdeg,
                                            const int* __restrict__ col,
                                            int node0, int l,
                                            u16 (* __restrict__ tile)[AT_STR]) {
    const int g = l >> 4;
    const int i = l & 15;
    // batch row metadata: 2 coalesced loads for all 16 nodes
    int rp = 0, rd = 0;
    {
        int n = node0 + l;
        bool v = (l < 16) && (n < N_NODES);
        rp = v ? row_ptr[n] : 0;
        rd = v ? rdeg[n] : 0;
    }
    // prefetch pair 0 col lists (pad lanes -> ZROW = zeroed feature row)
    int begA = __shfl(rp, 0, 64), degA = __shfl(rd, 0, 64);
    int begB = __shfl(rp, 1, 64), degB = __shfl(rd, 1, 64);
    int colvA = (l < min(degA, 64)) ? col[begA + l] : (int)ZROW;
    int colvB = (l < min(degB, 64)) ? col[begB + l] : (int)ZROW;
    for (int r = 0; r < 16; r += 2) {
        const int cbegA = begA, cdegA = degA, ccolA = colvA;
        const int cbegB = begB, cdegB = degB, ccolB = colvB;
        if (r < 14) {   // prefetch next pair (col latency hides under feats)
            begA = __shfl(rp, r + 2, 64); degA = __shfl(rd, r + 2, 64);
            begB = __shfl(rp, r + 3, 64); degB = __shfl(rd, r + 3, 64);
            colvA = (l < min(degA, 64)) ? col[begA + l] : (int)ZROW;
            colvB = (l < min(degB, 64)) ? col[begB + l] : (int)ZROW;
        }
        const int nbA = (min(cdegA, 64) + 15) & ~15;   // full 16-batches (ZROW pad)
        const int nbB = (min(cdegB, 64) + 15) & ~15;
        const int nbmax = max(nbA, nbB);   // joint to nbmax: pads are L1-hit ZROW
        float aA0 = 0.f, aA1 = 0.f, aA2 = 0.f, aA3 = 0.f;
        float aB0 = 0.f, aB1 = 0.f, aB2 = 0.f, aB3 = 0.f;
        for (int e = 0; e < nbmax; e += 16) {  // paired: 8 loads in flight, no tail
            int sA0 = __shfl(ccolA, e + g, 64);
            int sA1 = __shfl(ccolA, e + 4 + g, 64);
            int sA2 = __shfl(ccolA, e + 8 + g, 64);
            int sA3 = __shfl(ccolA, e + 12 + g, 64);
            int sB0 = __shfl(ccolB, e + g, 64);
            int sB1 = __shfl(ccolB, e + 4 + g, 64);
            int sB2 = __shfl(ccolB, e + 8 + g, 64);
            int sB3 = __shfl(ccolB, e + 12 + g, 64);
            unsigned vA0 = *(const unsigned*)(feat8 + (size_t)sA0 * F + i * 4);
            unsigned vA1 = *(const unsigned*)(feat8 + (size_t)sA1 * F + i * 4);
            unsigned vA2 = *(const unsigned*)(feat8 + (size_t)sA2 * F + i * 4);
            unsigned vA3 = *(const unsigned*)(feat8 + (size_t)sA3 * F + i * 4);
            unsigned vB0 = *(const unsigned*)(feat8 + (size_t)sB0 * F + i * 4);
            unsigned vB1 = *(const unsigned*)(feat8 + (size_t)sB1 * F + i * 4);
            unsigned vB2 = *(const unsigned*)(feat8 + (size_t)sB2 * F + i * 4);
            unsigned vB3 = *(const unsigned*)(feat8 + (size_t)sB3 * F + i * 4);
            f32x2 p0 = __builtin_amdgcn_cvt_pk_f32_fp8((int)vA0, false);
            f32x2 p1 = __builtin_amdgcn_cvt_pk_f32_fp8((int)vA0, true);
            f32x2 q0 = __builtin_amdgcn_cvt_pk_f32_fp8((int)vA1, false);
            f32x2 q1 = __builtin_amdgcn_cvt_pk_f32_fp8((int)vA1, true);
            f32x2 r0 = __builtin_amdgcn_cvt_pk_f32_fp8((int)vA2, false);
            f32x2 r1 = __builtin_amdgcn_cvt_pk_f32_fp8((int)vA2, true);
            f32x2 t0 = __builtin_amdgcn_cvt_pk_f32_fp8((int)vA3, false);
            f32x2 t1 = __builtin_amdgcn_cvt_pk_f32_fp8((int)vA3, true);
            aA0 += (p0.x + q0.x) + (r0.x + t0.x);
            aA1 += (p0.y + q0.y) + (r0.y + t0.y);
            aA2 += (p1.x + q1.x) + (r1.x + t1.x);
            aA3 += (p1.y + q1.y) + (r1.y + t1.y);
            f32x2 P0 = __builtin_amdgcn_cvt_pk_f32_fp8((int)vB0, false);
            f32x2 P1 = __builtin_amdgcn_cvt_pk_f32_fp8((int)vB0, true);
            f32x2 Q0 = __builtin_amdgcn_cvt_pk_f32_fp8((int)vB1, false);
            f32x2 Q1 = __builtin_amdgcn_cvt_pk_f32_fp8((int)vB1, true);
            f32x2 R0 = __builtin_amdgcn_cvt_pk_f32_fp8((int)vB2, false);
            f32x2 R1 = __builtin_amdgcn_cvt_pk_f32_fp8((int)vB2, true);
            f32x2 T0 = __builtin_amdgcn_cvt_pk_f32_fp8((int)vB3, false);
            f32x2 T1 = __builtin_amdgcn_cvt_pk_f32_fp8((int)vB3, true);
            aB0 += (P0.x + Q0.x) + (R0.x + T0.x);
            aB1 += (P0.y + Q0.y) + (R0.y + T0.y);
            aB2 += (P1.x + Q1.x) + (R1.x + T1.x);
            aB3 += (P1.y + Q1.y) + (R1.y + T1.y);
        }
        // deep rows (deg > 64): statistically never, kept for correctness
        for (int b2 = 64; b2 < cdegA; b2 += 64) {
            int c2 = min(cdegA - b2, 64);
            int cv = (l < c2) ? col[cbegA + b2 + l] : (int)ZROW;
            int nb2 = (c2 + 15) & ~15;
            for (int e2 = 0; e2 < nb2; e2 += 16)
                accum_one(feat8, cv, e2, g, i, aA0, aA1, aA2, aA3);
        }
        for (int b2 = 64; b2 < cdegB; b2 += 64) {
            int c2 = min(cdegB - b2, 64);
            int cv = (l < c2) ? col[cbegB + b2 + l] : (int)ZROW;
            int nb2 = (c2 + 15) & ~15;
            for (int e2 = 0; e2 < nb2; e2 += 16)
                accum_one(feat8, cv, e2, g, i, aB0, aB1, aB2, aB3);
        }
        // reduce quads and store both nodes
        aA0 += __shfl_xor(aA0, 16, 64); aA0 += __shfl_xor(aA0, 32, 64);
        aA1 += __shfl_xor(aA1, 16, 64); aA1 += __shfl_xor(aA1, 32, 64);
        aA2 += __shfl_xor(aA2, 16, 64); aA2 += __shfl_xor(aA2, 32, 64);
        aA3 += __shfl_xor(aA3, 16, 64); aA3 += __shfl_xor(aA3, 32, 64);
        aB0 += __shfl_xor(aB0, 16, 64); aB0 += __shfl_xor(aB0, 32, 64);
        aB1 += __shfl_xor(aB1, 16, 64); aB1 += __shfl_xor(aB1, 32, 64);
        aB2 += __shfl_xor(aB2, 16, 64); aB2 += __shfl_xor(aB2, 32, 64);
        aB3 += __shfl_xor(aB3, 16, 64); aB3 += __shfl_xor(aB3, 32, 64);
        if (g == 0) {
            ushort4 oA, oB;
            oA.x = f2bf(aA0); oA.y = f2bf(aA1); oA.z = f2bf(aA2); oA.w = f2bf(aA3);
            oB.x = f2bf(aB0); oB.y = f2bf(aB1); oB.z = f2bf(aB2); oB.w = f2bf(aB3);
            *(ushort4*)&tile[r][i * 4] = oA;       // zeros for pad/deg-0 nodes
            *(ushort4*)&tile[r + 1][i * 4] = oB;
        }
    }
}

__global__ void layer1_kernel(const u8* __restrict__ feat8,   // xf8
                              const u16* __restrict__ xbf,    // root input
                              const int* __restrict__ row_ptr,
                              const int* __restrict__ rdeg,
                              const int* __restrict__ col,
                              const u16* __restrict__ wcat,
                              const float* __restrict__ b_rel,
                              u16* __restrict__ h1bf,
                              u8* __restrict__ h1f8) {
    __shared__ u16 atile[4][16][AT_STR];   // 9.2 KB
    const int l = threadIdx.x & 63;
    const int wv = threadIdx.x >> 6;
    const int node0 = blockIdx.x * 64 + wv * 16;
    const int c = l & 15, quad = l >> 4;

    // hoist gather-independent loads: root fragments + bias hide under gather
    const size_t xrow = (size_t)(node0 + c) * F + quad * 8;  // pad rows masked below
    bf16x8 fa2 = *(const bf16x8*)(xbf + xrow);
    bf16x8 fa3 = *(const bf16x8*)(xbf + xrow + 32);
    float bias[4];
#pragma unroll
    for (int nt = 0; nt < 4; nt++) bias[nt] = b_rel[nt * 16 + c];

    gather_tile(feat8, row_ptr, rdeg, col, node0, l, atile[wv]);
    __syncthreads();

    // ---- MFMA: A = [aggr(LDS) | x(global)] ----
    bf16x8 fa0 = *(const bf16x8*)(&atile[wv][c][quad * 8]);
    bf16x8 fa1 = *(const bf16x8*)(&atile[wv][c][quad * 8 + 32]);

    f32x4 acc[4];
#pragma unroll
    for (int nt = 0; nt < 4; nt++) {
        const u16* wp = wcat + (size_t)(nt * 16 + c) * 128 + quad * 8;
        bf16x8 b0 = *(const bf16x8*)(wp);
        bf16x8 b1 = *(const bf16x8*)(wp + 32);
        bf16x8 b2 = *(const bf16x8*)(wp + 64);
        bf16x8 b3 = *(const bf16x8*)(wp + 96);
        f32x4 d = {0.f, 0.f, 0.f, 0.f};
        d = __builtin_amdgcn_mfma_f32_16x16x32_bf16(fa0, b0, d, 0, 0, 0);
        d = __builtin_amdgcn_mfma_f32_16x16x32_bf16(fa1, b1, d, 0, 0, 0);
        d = __builtin_amdgcn_mfma_f32_16x16x32_bf16(fa2, b2, d, 0, 0, 0);
        d = __builtin_amdgcn_mfma_f32_16x16x32_bf16(fa3, b3, d, 0, 0, 0);
        acc[nt] = d;
    }
#pragma unroll
    for (int nt = 0; nt < 4; nt++) {
        int f = nt * 16 + c;
#pragma unroll
        for (int r = 0; r < 4; r++) {
            int node = node0 + quad * 4 + r;
            if (node < N_NODES) {
                float v = fmaxf(acc[nt][r] + bias[nt], 0.f);
                h1bf[(size_t)node * F + f] = f2bf(v);
                h1f8[(size_t)node * F + f] = f2f8(v);
            }
        }
    }
}

__global__ void layer2_kernel(const u8* __restrict__ feat8,   // h1f8
                              const u16* __restrict__ h1bf,   // root input
                              const int* __restrict__ row_ptr,
                              const int* __restrict__ rdeg,
                              const int* __restrict__ col,
                              const u16* __restrict__ wcat,
                              const float* __restrict__ b_rel,
                              const float* __restrict__ outdegf,
                              float* __restrict__ partial2) {
    __shared__ u16 atile[4][16][AT_STR];   // 9.2 KB
    __shared__ float sR1[256], sR2[256];
    const int l = threadIdx.x & 63;
    const int wv = threadIdx.x >> 6;
    const int node0 = blockIdx.x * 64 + wv * 16;
    const int c = l & 15, quad = l >> 4;

    // hoist gather-independent loads
    const size_t xrow = (size_t)(node0 + c) * F + quad * 8;
    bf16x8 fa2 = *(const bf16x8*)(h1bf + xrow);
    bf16x8 fa3 = *(const bf16x8*)(h1bf + xrow + 32);
    float bias[4];
#pragma unroll
    for (int nt = 0; nt < 4; nt++) bias[nt] = b_rel[nt * 16 + c];
    float deg[4], val[4];
#pragma unroll
    for (int r = 0; r < 4; r++) {
        int node = node0 + quad * 4 + r;
        bool v = node < N_NODES;
        deg[r] = v ? outdegf[node] : 0.f;
        val[r] = v ? 1.f : 0.f;
    }

    gather_tile(feat8, row_ptr, rdeg, col, node0, l, atile[wv]);
    __syncthreads();

    bf16x8 fa0 = *(const bf16x8*)(&atile[wv][c][quad * 8]);
    bf16x8 fa1 = *(const bf16x8*)(&atile[wv][c][quad * 8 + 32]);

    f32x4 acc[4];
#pragma unroll
    for (int nt = 0; nt < 4; nt++) {
        const u16* wp = wcat + (size_t)(nt * 16 + c) * 128 + quad * 8;
        bf16x8 b0 = *(const bf16x8*)(wp);
        bf16x8 b1 = *(const bf16x8*)(wp + 32);
        bf16x8 b2 = *(const bf16x8*)(wp + 64);
        bf16x8 b3 = *(const bf16x8*)(wp + 96);
        f32x4 d = {0.f, 0.f, 0.f, 0.f};
        d = __builtin_amdgcn_mfma_f32_16x16x32_bf16(fa0, b0, d, 0, 0, 0);
        d = __builtin_amdgcn_mfma_f32_16x16x32_bf16(fa1, b1, d, 0, 0, 0);
        d = __builtin_amdgcn_mfma_f32_16x16x32_bf16(fa2, b2, d, 0, 0, 0);
        d = __builtin_amdgcn_mfma_f32_16x16x32_bf16(fa3, b3, d, 0, 0, 0);
        acc[nt] = d;
    }

    // collapsed layer-3: {sum outdeg*h2, sum h2} -> 16 global atomic slots
    float s1[4], s2[4];
#pragma unroll
    for (int nt = 0; nt < 4; nt++) {
        float t1 = 0.f, t2 = 0.f;
#pragma unroll
        for (int r = 0; r < 4; r++) {
            float v = fmaxf(acc[nt][r] + bias[nt], 0.f);  // relu kills pad noise
            t1 += deg[r] * v;
            t2 += val[r] * v;
        }
        t1 += __shfl_xor(t1, 16, 64);
        t1 += __shfl_xor(t1, 32, 64);
        t2 += __shfl_xor(t2, 16, 64);
        t2 += __shfl_xor(t2, 32, 64);
        s1[nt] = t1;
        s2[nt] = t2;
    }
    if (quad == 0) {
#pragma unroll
        for (int nt = 0; nt < 4; nt++) {
            sR1[wv * 64 + nt * 16 + c] = s1[nt];
            sR2[wv * 64 + nt * 16 + c] = s2[nt];
        }
    }
    __syncthreads();
    if (threadIdx.x < 64) {
        int f = threadIdx.x;
        float p1 = sR1[f] + sR1[64 + f] + sR1[128 + f] + sR1[192 + f];
        float p2 = sR2[f] + sR2[64 + f] + sR2[128 + f] + sR2[192 + f];
        const int slot = (blockIdx.x & (NSLOT - 1)) * 128;  // ~98 blocks/addr
        atomicAdd(&partial2[slot + f], p1);
        atomicAdd(&partial2[slot + 64 + f], p2);
    }
}

// Final: out = (S1 . w_rel3 + S2 . w_root3)/N + b3 from NSLOT x 128 partials.
__global__ void final_kernel(const float* __restrict__ partial2,
                             const float* __restrict__ w_rel3,
                             const float* __restrict__ b_rel3,
                             const float* __restrict__ w_root3,
                             float* __restrict__ out) {
    __shared__ float sT[128];
    const int t = threadIdx.x;  // 128 threads
    float s = 0.f;
#pragma unroll
    for (int k = 0; k < NSLOT; k++) s += partial2[k * 128 + t];
    sT[t] = s;
    __syncthreads();
    if (t < 64) {
        float v = sT[t] * w_rel3[t] + sT[64 + t] * w_root3[t];
        for (int off = 32; off > 0; off >>= 1) v += __shfl_down(v, off);
        if (t == 0) out[0] = v * (1.0f / (float)N_NODES) + b_rel3[0];
    }
}

extern "C" void kernel_launch(void* const* d_in, const int* in_sizes, int n_in,
                              void* d_out, int out_size, void* d_ws, size_t ws_size,
                              hipStream_t stream) {
    const float* x       = (const float*)d_in[0];
    const int*   edges   = (const int*)d_in[1];   // [2, E]: src row then dst row
    const float* w_rel1  = (const float*)d_in[2];
    const float* b_rel1  = (const float*)d_in[3];
    const float* w_root1 = (const float*)d_in[4];
    const float* w_rel2  = (const float*)d_in[5];
    const float* b_rel2  = (const float*)d_in[6];
    const float* w_root2 = (const float*)d_in[7];
    const float* w_rel3  = (const float*)d_in[8];
    const float* b_rel3  = (const float*)d_in[9];
    const float* w_root3 = (const float*)d_in[10];
    float* out = (float*)d_out;

    const size_t nfp = (size_t)NPAD * F;  // padded rows for maskless MFMA A-loads
    char* p = (char*)d_ws;
    u16*   xbf      = (u16*)p;                p += nfp * 2;                 // 12.8 MB
    u16*   h1bf     = (u16*)p;                p += nfp * 2;                 // 12.8 MB
    u8*    xf8      = (u8*)p;                 p += nfp;                     // 6.4 MB
    u8*    h1f8     = (u8*)p;                 p += nfp;                     // 6.4 MB
    int*   row_ptr  = (int*)p;                p += (size_t)N_NODES * 4;     // 0.4 MB
    int*   rdeg     = (int*)p;                p += (size_t)N_NODES * 4;     // 0.4 MB
    int*   col      = (int*)p;                p += (size_t)NBKT * CAP_B * 4; // 8.0 MB
    int*   ebuf     = (int*)p;                p += (size_t)NBKT * CAP_B * 4; // 8.0 MB
    int*   gcur_d   = (int*)p;                p += NBKT * 4;
    int*   gcur_s   = (int*)p;                p += NBKT * 4 + 8;            // pad align
    float* outdegf  = (float*)p;              p += (size_t)N_NODES * 4;     // 0.4 MB
    float* partial2 = (float*)p;              p += (size_t)NSLOT * 128 * 4; // 8 KB
    u16*   wcat1    = (u16*)p;                p += 64 * 128 * 2;            // 16 KB
    u16*   wcat2    = (u16*)p;                p += 64 * 128 * 2;            // 16 KB
    u8*    sbuf     = (u8*)p;                                              // 2.0 MB

    // ---- micro-init: cursors + partial2 + fp8 pad rows ----
    init_kernel<<<1, 256, 0, stream>>>(gcur_d, gcur_s, partial2, xf8, h1f8);

    // ---- counting sort: dst-CSR + src outdeg (burst writes, no glb atomics) ----
    countscat_kernel<<<ABLK, 256, 0, stream>>>(edges, gcur_d, gcur_s, ebuf, sbuf);

    // ---- csr finishing + cast/wprep streamed behind it ----
    csr_kernel<<<CSR_GRID, 256, 0, stream>>>(ebuf, gcur_d, sbuf, gcur_s,
                                             row_ptr, rdeg, col, outdegf,
                                             x, w_rel1, w_root1, w_rel2, w_root2,
                                             xbf, xf8, wcat1, wcat2);

    // layer 1: fused gather + transform (aggr never materialized)
    layer1_kernel<<<TBLK, 256, 0, stream>>>(xf8, xbf, row_ptr, rdeg, col,
                                            wcat1, b_rel1, h1bf, h1f8);

    // layer 2 + collapsed layer 3 (h2 never materialized)
    layer2_kernel<<<TBLK, 256, 0, stream>>>(h1f8, h1bf, row_ptr, rdeg, col,
                                            wcat2, b_rel2, outdegf, partial2);

    // single tiny final reduction
    final_kernel<<<1, 128, 0, stream>>>(partial2, w_rel3, b_rel3, w_root3, out);
}